// Round 11
// baseline (127.126 us; speedup 1.0000x reference)
//
#include <hip/hip_runtime.h>

#define IN_F 256
#define OUT_F 64
#define BLK1 512          // blocks in coarse passes (P1/P2)
#define BKT 128           // nodes per bucket
#define CAP 4096          // LDS edge-list capacity (bucket mean 1280, sigma~36)

typedef __attribute__((ext_vector_type(8))) short s16x8;
typedef __attribute__((ext_vector_type(4))) float f32x4;
typedef __attribute__((ext_vector_type(4))) unsigned u32x4;

__device__ __forceinline__ unsigned short bf16_rne(float f) {
    unsigned u = __builtin_bit_cast(unsigned, f);
    u += 0x7FFFu + ((u >> 16) & 1u);
    return (unsigned short)(u >> 16);
}
__device__ __forceinline__ float bf16_lo(unsigned u) {
    return __builtin_bit_cast(float, u << 16);
}
__device__ __forceinline__ float bf16_hi(unsigned u) {
    return __builtin_bit_cast(float, u & 0xFFFF0000u);
}
// packed f32x2 -> bf16x2 (RNE), single VALU op
__device__ __forceinline__ unsigned pk2(float a, float b) {
    unsigned r;
    asm("v_cvt_pk_bf16_f32 %0, %1, %2" : "=v"(r) : "v"(a), "v"(b));
    return r;
}

// ---------------------------------------------------------------------------
// P1: per-block coarse-bucket histograms (bucket = node>>7) for dst AND src.
// ---------------------------------------------------------------------------
__global__ __launch_bounds__(256) void k_coarse(const int* __restrict__ src,
                                                const int* __restrict__ dst,
                                                int* __restrict__ cnt,
                                                int nb, int ne) {
    __shared__ int hD[1024], hS[1024];
    const int blk = blockIdx.x, tid = threadIdx.x;
    for (int i = tid; i < 1024; i += 256) { hD[i] = 0; hS[i] = 0; }
    __syncthreads();
    const int epb = (ne + BLK1 - 1) / BLK1;
    const int e0 = blk * epb, e1 = min(ne, e0 + epb);
    for (int e = e0 + tid; e < e1; e += 256) {
        atomicAdd(&hD[dst[e] >> 7], 1);
        atomicAdd(&hS[src[e] >> 7], 1);
    }
    __syncthreads();
    for (int bb = tid; bb < nb; bb += 256) {
        cnt[bb * BLK1 + blk] = hD[bb];
        cnt[(nb + bb) * BLK1 + blk] = hS[bb];
    }
}

// ---------------------------------------------------------------------------
// Exclusive scan over m = 2*nb*BLK1 elements; partial add folded into consumers.
// ---------------------------------------------------------------------------
__global__ __launch_bounds__(256) void k_scan1(const int* __restrict__ deg,
                                               int* __restrict__ excl,
                                               int* __restrict__ partials, int m) {
    __shared__ int sd[256];
    const int tid = threadIdx.x;
    const int idx = blockIdx.x * 1024 + tid * 4;
    int v0 = 0, v1 = 0, v2 = 0, v3 = 0;
    if (idx     < m) v0 = deg[idx];
    if (idx + 1 < m) v1 = deg[idx + 1];
    if (idx + 2 < m) v2 = deg[idx + 2];
    if (idx + 3 < m) v3 = deg[idx + 3];
    const int tsum = v0 + v1 + v2 + v3;
    sd[tid] = tsum;
    __syncthreads();
    for (int off = 1; off < 256; off <<= 1) {
        int t = (tid >= off) ? sd[tid - off] : 0;
        __syncthreads();
        sd[tid] += t;
        __syncthreads();
    }
    const int texcl = sd[tid] - tsum;
    if (tid == 255) partials[blockIdx.x] = sd[255];
    if (idx     < m) excl[idx]     = texcl;
    if (idx + 1 < m) excl[idx + 1] = texcl + v0;
    if (idx + 2 < m) excl[idx + 2] = texcl + v0 + v1;
    if (idx + 3 < m) excl[idx + 3] = texcl + v0 + v1 + v2;
}

__global__ __launch_bounds__(1024) void k_scan2(int* __restrict__ partials, int nb) {
    __shared__ int sd[1024];
    const int tid = threadIdx.x;
    const int v = (tid < nb) ? partials[tid] : 0;
    sd[tid] = v;
    __syncthreads();
    for (int off = 1; off < 1024; off <<= 1) {
        int t = (tid >= off) ? sd[tid - off] : 0;
        __syncthreads();
        sd[tid] += t;
        __syncthreads();
    }
    if (tid < nb) partials[tid] = sd[tid] - v;  // exclusive
}

// ---------------------------------------------------------------------------
// P2: partition edges into coarse buckets via LDS cursors.
// dst entry: (dst&127)<<17 | src; src entry: src&127.
// ---------------------------------------------------------------------------
__global__ __launch_bounds__(256) void k_part(const int* __restrict__ src,
                                              const int* __restrict__ dst,
                                              const int* __restrict__ cnt,
                                              const int* __restrict__ partials,
                                              unsigned* __restrict__ tmp,
                                              int nb, int ne) {
    __shared__ int cD[1024], cS[1024];
    const int blk = blockIdx.x, tid = threadIdx.x;
    for (int bb = tid; bb < nb; bb += 256) {
        int iD = bb * BLK1 + blk;
        int iS = (nb + bb) * BLK1 + blk;
        cD[bb] = cnt[iD] + partials[iD >> 10];
        cS[bb] = cnt[iS] + partials[iS >> 10];
    }
    __syncthreads();
    const int epb = (ne + BLK1 - 1) / BLK1;
    const int e0 = blk * epb, e1 = min(ne, e0 + epb);
    for (int e = e0 + tid; e < e1; e += 256) {
        int d = dst[e], s = src[e];
        int pD = atomicAdd(&cD[d >> 7], 1);
        tmp[pD] = ((unsigned)(d & 127) << 17) | (unsigned)s;
        int pS = atomicAdd(&cS[s >> 7], 1);
        tmp[pS] = (unsigned)(s & 127);
    }
}

// ---------------------------------------------------------------------------
// P3-src: one block per bucket. LDS histogram of src entries -> deg_out.
// ---------------------------------------------------------------------------
__global__ __launch_bounds__(256) void k_fine_src(const int* __restrict__ cnt,
                                                  const int* __restrict__ partials,
                                                  const unsigned* __restrict__ tmp,
                                                  int* __restrict__ deg_out,
                                                  int n, int nb, int ne) {
    __shared__ int hist[BKT];
    const int b = blockIdx.x, tid = threadIdx.x;
    const int ib = (nb + b) * BLK1;
    const int base = cnt[ib] + partials[ib >> 10];
    const int ie = (nb + b + 1) * BLK1;
    const int end = (b + 1 < nb) ? (cnt[ie] + partials[ie >> 10]) : 2 * ne;
    if (tid < BKT) hist[tid] = 0;
    __syncthreads();
    for (int i = base + tid; i < end; i += 256)
        atomicAdd(&hist[tmp[i] & 127u], 1);
    __syncthreads();
    const int node = b * BKT + tid;
    if (tid < BKT && node < n) deg_out[node] = hist[tid];
}

// ---------------------------------------------------------------------------
// GEMM: h(bf16) = (X @ W) * rsqrt(max(deg_out,1)) row-scale at OUTPUT.
// A-fragments from global, v_cvt_pk_bf16_f32 conversion (2 elems/op);
// W^T (32 KB bf16, XOR-swizzled) in LDS; 2 row-tiles of 64 per block.
// ---------------------------------------------------------------------------
__global__ __launch_bounds__(256, 4) void k_gemm(const float* __restrict__ x,
                                                 const float* __restrict__ W,
                                                 const int* __restrict__ deg_out,
                                                 unsigned short* __restrict__ h, int n) {
    __shared__ char lds[32768];
    const int tid = threadIdx.x;
    const int lane = tid & 63;
    const int wid = tid >> 6;

    {
        const int f = tid & 63;
        const int kg = (tid >> 6) * 64;
        const int swz = (f & 7) << 4;
#pragma unroll
        for (int j = 0; j < 16; ++j) {
            const int k0 = kg + j * 4;
            float w0 = W[(k0 + 0) * OUT_F + f];
            float w1 = W[(k0 + 1) * OUT_F + f];
            float w2 = W[(k0 + 2) * OUT_F + f];
            float w3 = W[(k0 + 3) * OUT_F + f];
            uint2 p;
            p.x = pk2(w0, w1);
            p.y = pk2(w2, w3);
            *(uint2*)(lds + f * 512 + ((k0 * 2) ^ swz)) = p;
        }
    }
    __syncthreads();

    const int r15 = lane & 15;           // A row within 16 / B col within 16
    const int q = lane >> 4;             // k-quarter
    const int bswz = (r15 & 7) << 4;
    const int b_base = r15 * 512;
    const int rq = q * 4;

#pragma unroll
    for (int p = 0; p < 2; ++p) {
        const int row = blockIdx.x * 128 + p * 64 + wid * 16 + r15;
        const int rowc = min(row, n - 1);                  // clamp (stores guarded)
        const float* xr = x + (size_t)rowc * IN_F + q * 8;

        f32x4 acc0 = {0.f, 0.f, 0.f, 0.f};
        f32x4 acc1 = acc0, acc2 = acc0, acc3 = acc0;

#pragma unroll
        for (int kk = 0; kk < 8; ++kk) {
            float4 a0 = *(const float4*)(xr + kk * 32);
            float4 a1 = *(const float4*)(xr + kk * 32 + 4);
            u32x4 au;
            au[0] = pk2(a0.x, a0.y);
            au[1] = pk2(a0.z, a0.w);
            au[2] = pk2(a1.x, a1.y);
            au[3] = pk2(a1.z, a1.w);
            s16x8 a = __builtin_bit_cast(s16x8, au);
            const int off = (q * 16 + kk * 64) ^ bswz;     // XOR in bits 4-6: carry-free
            s16x8 b0 = *(const s16x8*)(lds + b_base + off);
            s16x8 b1 = *(const s16x8*)(lds + b_base + 8192 + off);
            s16x8 b2 = *(const s16x8*)(lds + b_base + 16384 + off);
            s16x8 b3 = *(const s16x8*)(lds + b_base + 24576 + off);
            acc0 = __builtin_amdgcn_mfma_f32_16x16x32_bf16(a, b0, acc0, 0, 0, 0);
            acc1 = __builtin_amdgcn_mfma_f32_16x16x32_bf16(a, b1, acc1, 0, 0, 0);
            acc2 = __builtin_amdgcn_mfma_f32_16x16x32_bf16(a, b2, acc2, 0, 0, 0);
            acc3 = __builtin_amdgcn_mfma_f32_16x16x32_bf16(a, b3, acc3, 0, 0, 0);
        }

        // D layout: row=(lane>>4)*4+j, col=lane&15 (m89-verified); scale at output
#pragma unroll
        for (int j = 0; j < 4; ++j) {
            const int grow = blockIdx.x * 128 + p * 64 + wid * 16 + rq + j;
            if (grow < n) {
                const float s = rsqrtf(fmaxf((float)deg_out[grow], 1.0f));
                unsigned short* hp = h + (size_t)grow * OUT_F + r15;
                hp[0]  = bf16_rne(acc0[j] * s);
                hp[16] = bf16_rne(acc1[j] * s);
                hp[32] = bf16_rne(acc2[j] * s);
                hp[48] = bf16_rne(acc3[j] * s);
            }
        }
    }
}

// ---------------------------------------------------------------------------
// Fused fine-sort + aggregate: one 512-thread block per 128-node dst bucket.
// Phase A: LDS hist -> LDS scan -> LDS-cursor scatter into eidx[CAP].
// Phase B v2: 8 edges per wave-step. Lane (eslot=lane>>3, j=lane&7): each lane
// dwordx4-gathers 16 B (8 bf16 feats) of row eidx[st+i+eslot] -> 64 lanes
// cover 8 full 128 B rows per instruction (4x deeper MLP than half-wave
// scheme). 8 f32 acc/lane; one shfl_xor(8/16/32) tree per NODE; lanes
// eslot==0 write 32 B coalesced with scale+bias fused. Bias hoisted.
// ---------------------------------------------------------------------------
__global__ __launch_bounds__(512) void k_agg(const int* __restrict__ cnt,
                                             const int* __restrict__ partials,
                                             const unsigned* __restrict__ tmp,
                                             const unsigned* __restrict__ h32,
                                             const float* __restrict__ b,
                                             float* __restrict__ out,
                                             int n, int nb, int ne) {
    __shared__ int hist[BKT], sd[BKT], cur[BKT], stt[BKT];
    __shared__ int eidx[CAP];            // 16 KB
    const int bkt = blockIdx.x, tid = threadIdx.x;
    const int ib = bkt * BLK1;
    const int base = cnt[ib] + partials[ib >> 10];
    const int ie = (bkt + 1) * BLK1;
    const int end = (bkt + 1 < nb) ? (cnt[ie] + partials[ie >> 10]) : ne;

    if (tid < BKT) hist[tid] = 0;
    __syncthreads();
    for (int i = base + tid; i < end; i += 512)
        atomicAdd(&hist[tmp[i] >> 17], 1);
    __syncthreads();
    int dg0 = 0;
    if (tid < BKT) { dg0 = hist[tid]; sd[tid] = dg0; }
    __syncthreads();
    for (int off = 1; off < BKT; off <<= 1) {
        int t = 0;
        if (tid < BKT && tid >= off) t = sd[tid - off];
        __syncthreads();
        if (tid < BKT) sd[tid] += t;
        __syncthreads();
    }
    if (tid < BKT) {
        const int excl = sd[tid] - dg0;
        cur[tid] = excl;
        stt[tid] = excl;
    }
    __syncthreads();
    for (int i = base + tid; i < end; i += 512) {
        unsigned v = tmp[i];
        int pos = atomicAdd(&cur[v >> 17], 1);
        eidx[min(pos, CAP - 1)] = (int)(v & 0x1FFFFu);
    }
    __syncthreads();

    const int wid = tid >> 6, lane = tid & 63;
    const int eslot = lane >> 3;         // edge slot 0..7
    const int j = lane & 7;              // feat group: feats [8j, 8j+8)
    // hoist bias for this lane's 8 feats
    float4 bv0 = *(const float4*)&b[j * 8];
    float4 bv1 = *(const float4*)&b[j * 8 + 4];

    for (int nd = wid; nd < BKT; nd += 8) {
        const int node = bkt * BKT + nd;
        if (node >= n) continue;
        const int st = stt[nd];
        const int dg = hist[nd];
        float a0 = 0.f, a1 = 0.f, a2 = 0.f, a3 = 0.f;
        float a4 = 0.f, a5 = 0.f, a6 = 0.f, a7 = 0.f;
        for (int i = 0; i < dg; i += 8) {
            const int e = i + eslot;
            const bool valid = e < dg;
            const int s = eidx[st + (valid ? e : (dg - 1))];
            u32x4 u = *(const u32x4*)(h32 + (size_t)s * 32 + j * 4);
            if (!valid) { u[0] = 0; u[1] = 0; u[2] = 0; u[3] = 0; }
            a0 += bf16_lo(u[0]); a1 += bf16_hi(u[0]);
            a2 += bf16_lo(u[1]); a3 += bf16_hi(u[1]);
            a4 += bf16_lo(u[2]); a5 += bf16_hi(u[2]);
            a6 += bf16_lo(u[3]); a7 += bf16_hi(u[3]);
        }
        // reduce across the 8 edge slots
        a0 += __shfl_xor(a0, 8, 64); a1 += __shfl_xor(a1, 8, 64);
        a2 += __shfl_xor(a2, 8, 64); a3 += __shfl_xor(a3, 8, 64);
        a4 += __shfl_xor(a4, 8, 64); a5 += __shfl_xor(a5, 8, 64);
        a6 += __shfl_xor(a6, 8, 64); a7 += __shfl_xor(a7, 8, 64);
        a0 += __shfl_xor(a0, 16, 64); a1 += __shfl_xor(a1, 16, 64);
        a2 += __shfl_xor(a2, 16, 64); a3 += __shfl_xor(a3, 16, 64);
        a4 += __shfl_xor(a4, 16, 64); a5 += __shfl_xor(a5, 16, 64);
        a6 += __shfl_xor(a6, 16, 64); a7 += __shfl_xor(a7, 16, 64);
        a0 += __shfl_xor(a0, 32, 64); a1 += __shfl_xor(a1, 32, 64);
        a2 += __shfl_xor(a2, 32, 64); a3 += __shfl_xor(a3, 32, 64);
        a4 += __shfl_xor(a4, 32, 64); a5 += __shfl_xor(a5, 32, 64);
        a6 += __shfl_xor(a6, 32, 64); a7 += __shfl_xor(a7, 32, 64);

        if (eslot == 0) {
            const float scale = rsqrtf(fmaxf((float)dg, 1.0f));
            float4 v0, v1;
            v0.x = a0 * scale + bv0.x;
            v0.y = a1 * scale + bv0.y;
            v0.z = a2 * scale + bv0.z;
            v0.w = a3 * scale + bv0.w;
            v1.x = a4 * scale + bv1.x;
            v1.y = a5 * scale + bv1.y;
            v1.z = a6 * scale + bv1.z;
            v1.w = a7 * scale + bv1.w;
            float* op = &out[(size_t)node * OUT_F + j * 8];
            *(float4*)op = v0;
            *(float4*)(op + 4) = v1;
        }
    }
}

extern "C" void kernel_launch(void* const* d_in, const int* in_sizes, int n_in,
                              void* d_out, int out_size, void* d_ws, size_t ws_size,
                              hipStream_t stream) {
    const float* x   = (const float*)d_in[0];
    const int*   src = (const int*)d_in[1];
    const int*   dst = (const int*)d_in[2];
    const float* W   = (const float*)d_in[3];
    const float* b   = (const float*)d_in[4];
    float* out = (float*)d_out;

    const int n  = in_sizes[0] / IN_F;   // 100000
    const int ne = in_sizes[1];          // 1000000

    const int nb = (n + BKT - 1) / BKT;  // 782 buckets (<= 1024)
    const int m  = 2 * nb * BLK1;        // cnt matrix size (800768)

    int* cnt        = (int*)d_ws;                  // m
    int* partials   = cnt + m;                     // 1024
    unsigned* tmp   = (unsigned*)(partials + 1024);// 2*ne
    int* deg_out    = (int*)(tmp + 2 * (size_t)ne);// n
    unsigned short* h = (unsigned short*)(deg_out + n);  // n*64 bf16

    const int nb_scan = (m + 1023) / 1024;         // 782 (<= 1024)

    k_coarse<<<BLK1, 256, 0, stream>>>(src, dst, cnt, nb, ne);
    k_scan1<<<nb_scan, 256, 0, stream>>>(cnt, cnt, partials, m);
    k_scan2<<<1, 1024, 0, stream>>>(partials, nb_scan);
    k_part<<<BLK1, 256, 0, stream>>>(src, dst, cnt, partials, tmp, nb, ne);
    k_fine_src<<<nb, 256, 0, stream>>>(cnt, partials, tmp, deg_out, n, nb, ne);
    k_gemm<<<(n + 127) / 128, 256, 0, stream>>>(x, W, deg_out, h, n);
    k_agg<<<nb, 512, 0, stream>>>(cnt, partials, tmp, (const unsigned*)h, b, out, n, nb, ne);
}

// Round 12
// 117.163 us; speedup vs baseline: 1.0850x; 1.0850x over previous
//
#include <hip/hip_runtime.h>

#define IN_F 256
#define OUT_F 64
#define BLK1 512          // blocks in coarse passes (P1/P2)
#define BKT 128           // nodes per bucket
#define CAP 4096          // LDS edge-list capacity (bucket mean 1280, sigma~36)

typedef __attribute__((ext_vector_type(8))) short s16x8;
typedef __attribute__((ext_vector_type(4))) float f32x4;
typedef __attribute__((ext_vector_type(4))) unsigned u32x4;

__device__ __forceinline__ unsigned short bf16_rne(float f) {
    unsigned u = __builtin_bit_cast(unsigned, f);
    u += 0x7FFFu + ((u >> 16) & 1u);
    return (unsigned short)(u >> 16);
}
__device__ __forceinline__ float bf16_lo(unsigned u) {
    return __builtin_bit_cast(float, u << 16);
}
__device__ __forceinline__ float bf16_hi(unsigned u) {
    return __builtin_bit_cast(float, u & 0xFFFF0000u);
}
// packed f32x2 -> bf16x2 (RNE), single VALU op
__device__ __forceinline__ unsigned pk2(float a, float b) {
    unsigned r;
    asm("v_cvt_pk_bf16_f32 %0, %1, %2" : "=v"(r) : "v"(a), "v"(b));
    return r;
}

// ---------------------------------------------------------------------------
// P1: per-block coarse-bucket histograms (bucket = node>>7) for dst AND src.
// ---------------------------------------------------------------------------
__global__ __launch_bounds__(256) void k_coarse(const int* __restrict__ src,
                                                const int* __restrict__ dst,
                                                int* __restrict__ cnt,
                                                int nb, int ne) {
    __shared__ int hD[1024], hS[1024];
    const int blk = blockIdx.x, tid = threadIdx.x;
    for (int i = tid; i < 1024; i += 256) { hD[i] = 0; hS[i] = 0; }
    __syncthreads();
    const int epb = (ne + BLK1 - 1) / BLK1;
    const int e0 = blk * epb, e1 = min(ne, e0 + epb);
    for (int e = e0 + tid; e < e1; e += 256) {
        atomicAdd(&hD[dst[e] >> 7], 1);
        atomicAdd(&hS[src[e] >> 7], 1);
    }
    __syncthreads();
    for (int bb = tid; bb < nb; bb += 256) {
        cnt[bb * BLK1 + blk] = hD[bb];
        cnt[(nb + bb) * BLK1 + blk] = hS[bb];
    }
}

// ---------------------------------------------------------------------------
// Exclusive scan over m = 2*nb*BLK1 elements; partial add folded into consumers.
// ---------------------------------------------------------------------------
__global__ __launch_bounds__(256) void k_scan1(const int* __restrict__ deg,
                                               int* __restrict__ excl,
                                               int* __restrict__ partials, int m) {
    __shared__ int sd[256];
    const int tid = threadIdx.x;
    const int idx = blockIdx.x * 1024 + tid * 4;
    int v0 = 0, v1 = 0, v2 = 0, v3 = 0;
    if (idx     < m) v0 = deg[idx];
    if (idx + 1 < m) v1 = deg[idx + 1];
    if (idx + 2 < m) v2 = deg[idx + 2];
    if (idx + 3 < m) v3 = deg[idx + 3];
    const int tsum = v0 + v1 + v2 + v3;
    sd[tid] = tsum;
    __syncthreads();
    for (int off = 1; off < 256; off <<= 1) {
        int t = (tid >= off) ? sd[tid - off] : 0;
        __syncthreads();
        sd[tid] += t;
        __syncthreads();
    }
    const int texcl = sd[tid] - tsum;
    if (tid == 255) partials[blockIdx.x] = sd[255];
    if (idx     < m) excl[idx]     = texcl;
    if (idx + 1 < m) excl[idx + 1] = texcl + v0;
    if (idx + 2 < m) excl[idx + 2] = texcl + v0 + v1;
    if (idx + 3 < m) excl[idx + 3] = texcl + v0 + v1 + v2;
}

__global__ __launch_bounds__(1024) void k_scan2(int* __restrict__ partials, int nb) {
    __shared__ int sd[1024];
    const int tid = threadIdx.x;
    const int v = (tid < nb) ? partials[tid] : 0;
    sd[tid] = v;
    __syncthreads();
    for (int off = 1; off < 1024; off <<= 1) {
        int t = (tid >= off) ? sd[tid - off] : 0;
        __syncthreads();
        sd[tid] += t;
        __syncthreads();
    }
    if (tid < nb) partials[tid] = sd[tid] - v;  // exclusive
}

// ---------------------------------------------------------------------------
// P2: partition edges into coarse buckets via LDS cursors.
// dst entry: (dst&127)<<17 | src; src entry: src&127.
// ---------------------------------------------------------------------------
__global__ __launch_bounds__(256) void k_part(const int* __restrict__ src,
                                              const int* __restrict__ dst,
                                              const int* __restrict__ cnt,
                                              const int* __restrict__ partials,
                                              unsigned* __restrict__ tmp,
                                              int nb, int ne) {
    __shared__ int cD[1024], cS[1024];
    const int blk = blockIdx.x, tid = threadIdx.x;
    for (int bb = tid; bb < nb; bb += 256) {
        int iD = bb * BLK1 + blk;
        int iS = (nb + bb) * BLK1 + blk;
        cD[bb] = cnt[iD] + partials[iD >> 10];
        cS[bb] = cnt[iS] + partials[iS >> 10];
    }
    __syncthreads();
    const int epb = (ne + BLK1 - 1) / BLK1;
    const int e0 = blk * epb, e1 = min(ne, e0 + epb);
    for (int e = e0 + tid; e < e1; e += 256) {
        int d = dst[e], s = src[e];
        int pD = atomicAdd(&cD[d >> 7], 1);
        tmp[pD] = ((unsigned)(d & 127) << 17) | (unsigned)s;
        int pS = atomicAdd(&cS[s >> 7], 1);
        tmp[pS] = (unsigned)(s & 127);
    }
}

// ---------------------------------------------------------------------------
// P3-src: one block per bucket. LDS histogram of src entries -> deg_out.
// ---------------------------------------------------------------------------
__global__ __launch_bounds__(256) void k_fine_src(const int* __restrict__ cnt,
                                                  const int* __restrict__ partials,
                                                  const unsigned* __restrict__ tmp,
                                                  int* __restrict__ deg_out,
                                                  int n, int nb, int ne) {
    __shared__ int hist[BKT];
    const int b = blockIdx.x, tid = threadIdx.x;
    const int ib = (nb + b) * BLK1;
    const int base = cnt[ib] + partials[ib >> 10];
    const int ie = (nb + b + 1) * BLK1;
    const int end = (b + 1 < nb) ? (cnt[ie] + partials[ie >> 10]) : 2 * ne;
    if (tid < BKT) hist[tid] = 0;
    __syncthreads();
    for (int i = base + tid; i < end; i += 256)
        atomicAdd(&hist[tmp[i] & 127u], 1);
    __syncthreads();
    const int node = b * BKT + tid;
    if (tid < BKT && node < n) deg_out[node] = hist[tid];
}

// ---------------------------------------------------------------------------
// GEMM: h(bf16) = (X @ W) * rsqrt(max(deg_out,1)) row-scale at OUTPUT.
// A-fragments from global, v_cvt_pk_bf16_f32 conversion (2 elems/op);
// W^T (32 KB bf16, XOR-swizzled) in LDS; 2 row-tiles of 64 per block.
// ---------------------------------------------------------------------------
__global__ __launch_bounds__(256, 4) void k_gemm(const float* __restrict__ x,
                                                 const float* __restrict__ W,
                                                 const int* __restrict__ deg_out,
                                                 unsigned short* __restrict__ h, int n) {
    __shared__ char lds[32768];
    const int tid = threadIdx.x;
    const int lane = tid & 63;
    const int wid = tid >> 6;

    {
        const int f = tid & 63;
        const int kg = (tid >> 6) * 64;
        const int swz = (f & 7) << 4;
#pragma unroll
        for (int j = 0; j < 16; ++j) {
            const int k0 = kg + j * 4;
            float w0 = W[(k0 + 0) * OUT_F + f];
            float w1 = W[(k0 + 1) * OUT_F + f];
            float w2 = W[(k0 + 2) * OUT_F + f];
            float w3 = W[(k0 + 3) * OUT_F + f];
            uint2 p;
            p.x = pk2(w0, w1);
            p.y = pk2(w2, w3);
            *(uint2*)(lds + f * 512 + ((k0 * 2) ^ swz)) = p;
        }
    }
    __syncthreads();

    const int r15 = lane & 15;           // A row within 16 / B col within 16
    const int q = lane >> 4;             // k-quarter
    const int bswz = (r15 & 7) << 4;
    const int b_base = r15 * 512;
    const int rq = q * 4;

#pragma unroll
    for (int p = 0; p < 2; ++p) {
        const int row = blockIdx.x * 128 + p * 64 + wid * 16 + r15;
        const int rowc = min(row, n - 1);                  // clamp (stores guarded)
        const float* xr = x + (size_t)rowc * IN_F + q * 8;

        f32x4 acc0 = {0.f, 0.f, 0.f, 0.f};
        f32x4 acc1 = acc0, acc2 = acc0, acc3 = acc0;

#pragma unroll
        for (int kk = 0; kk < 8; ++kk) {
            float4 a0 = *(const float4*)(xr + kk * 32);
            float4 a1 = *(const float4*)(xr + kk * 32 + 4);
            u32x4 au;
            au[0] = pk2(a0.x, a0.y);
            au[1] = pk2(a0.z, a0.w);
            au[2] = pk2(a1.x, a1.y);
            au[3] = pk2(a1.z, a1.w);
            s16x8 a = __builtin_bit_cast(s16x8, au);
            const int off = (q * 16 + kk * 64) ^ bswz;     // XOR in bits 4-6: carry-free
            s16x8 b0 = *(const s16x8*)(lds + b_base + off);
            s16x8 b1 = *(const s16x8*)(lds + b_base + 8192 + off);
            s16x8 b2 = *(const s16x8*)(lds + b_base + 16384 + off);
            s16x8 b3 = *(const s16x8*)(lds + b_base + 24576 + off);
            acc0 = __builtin_amdgcn_mfma_f32_16x16x32_bf16(a, b0, acc0, 0, 0, 0);
            acc1 = __builtin_amdgcn_mfma_f32_16x16x32_bf16(a, b1, acc1, 0, 0, 0);
            acc2 = __builtin_amdgcn_mfma_f32_16x16x32_bf16(a, b2, acc2, 0, 0, 0);
            acc3 = __builtin_amdgcn_mfma_f32_16x16x32_bf16(a, b3, acc3, 0, 0, 0);
        }

        // D layout: row=(lane>>4)*4+j, col=lane&15 (m89-verified); scale at output
#pragma unroll
        for (int j = 0; j < 4; ++j) {
            const int grow = blockIdx.x * 128 + p * 64 + wid * 16 + rq + j;
            if (grow < n) {
                const float s = rsqrtf(fmaxf((float)deg_out[grow], 1.0f));
                unsigned short* hp = h + (size_t)grow * OUT_F + r15;
                hp[0]  = bf16_rne(acc0[j] * s);
                hp[16] = bf16_rne(acc1[j] * s);
                hp[32] = bf16_rne(acc2[j] * s);
                hp[48] = bf16_rne(acc3[j] * s);
            }
        }
    }
}

// ---------------------------------------------------------------------------
// Fused fine-sort + aggregate: one 512-thread block per 128-node dst bucket.
// Phase A: LDS hist -> LDS scan -> LDS-cursor scatter into eidx[CAP].
// Phase B (R10 layout + deeper unroll): half-wave per edge, dword (2 feats)
// per lane; 8-edge unroll = 4 independent load chains; 4 acc pairs merged
// with 3 adds; reduction stays exactly 2 shfl_xor per node.
// ---------------------------------------------------------------------------
__global__ __launch_bounds__(512) void k_agg(const int* __restrict__ cnt,
                                             const int* __restrict__ partials,
                                             const unsigned* __restrict__ tmp,
                                             const unsigned* __restrict__ h32,
                                             const float* __restrict__ b,
                                             float* __restrict__ out,
                                             int n, int nb, int ne) {
    __shared__ int hist[BKT], sd[BKT], cur[BKT], stt[BKT];
    __shared__ int eidx[CAP];            // 16 KB
    const int bkt = blockIdx.x, tid = threadIdx.x;
    const int ib = bkt * BLK1;
    const int base = cnt[ib] + partials[ib >> 10];
    const int ie = (bkt + 1) * BLK1;
    const int end = (bkt + 1 < nb) ? (cnt[ie] + partials[ie >> 10]) : ne;

    if (tid < BKT) hist[tid] = 0;
    __syncthreads();
    for (int i = base + tid; i < end; i += 512)
        atomicAdd(&hist[tmp[i] >> 17], 1);
    __syncthreads();
    int dg0 = 0;
    if (tid < BKT) { dg0 = hist[tid]; sd[tid] = dg0; }
    __syncthreads();
    for (int off = 1; off < BKT; off <<= 1) {
        int t = 0;
        if (tid < BKT && tid >= off) t = sd[tid - off];
        __syncthreads();
        if (tid < BKT) sd[tid] += t;
        __syncthreads();
    }
    if (tid < BKT) {
        const int excl = sd[tid] - dg0;
        cur[tid] = excl;
        stt[tid] = excl;
    }
    __syncthreads();
    for (int i = base + tid; i < end; i += 512) {
        unsigned v = tmp[i];
        int pos = atomicAdd(&cur[v >> 17], 1);
        eidx[min(pos, CAP - 1)] = (int)(v & 0x1FFFFu);
    }
    __syncthreads();

    const int wid = tid >> 6, lane = tid & 63;
    const int f2 = lane & 31, half = lane >> 5;
    for (int nd = wid; nd < BKT; nd += 8) {
        const int node = bkt * BKT + nd;
        if (node >= n) continue;
        const int st = stt[nd];
        const int dg = hist[nd];
        float a0 = 0.f, a1 = 0.f, c0 = 0.f, c1 = 0.f;
        float d0 = 0.f, d1 = 0.f, e0 = 0.f, e1 = 0.f;
        int i = 0;
        const int dg8 = dg & ~7;
        for (; i < dg8; i += 8) {        // 8 edges, 4 independent chains
            int s0 = eidx[st + i + half];
            int s1 = eidx[st + i + 2 + half];
            int s2 = eidx[st + i + 4 + half];
            int s3 = eidx[st + i + 6 + half];
            unsigned u0 = h32[s0 * 32 + f2];
            unsigned u1 = h32[s1 * 32 + f2];
            unsigned u2 = h32[s2 * 32 + f2];
            unsigned u3 = h32[s3 * 32 + f2];
            a0 += bf16_lo(u0); a1 += bf16_hi(u0);
            c0 += bf16_lo(u1); c1 += bf16_hi(u1);
            d0 += bf16_lo(u2); d1 += bf16_hi(u2);
            e0 += bf16_lo(u3); e1 += bf16_hi(u3);
        }
        for (; i < dg; i += 2) {         // predicated tail (up to 7 edges)
            const int e = i + half;
            const bool v = e < dg;
            int s = eidx[st + (v ? e : i)];
            unsigned u = h32[s * 32 + f2];
            if (v) { a0 += bf16_lo(u); a1 += bf16_hi(u); }
        }
        a0 += c0; a1 += c1;
        d0 += e0; d1 += e1;
        a0 += d0; a1 += d1;
        a0 += __shfl_xor(a0, 32, 64);
        a1 += __shfl_xor(a1, 32, 64);
        if (half == 0) {
            const float scale = rsqrtf(fmaxf((float)dg, 1.0f));
            float2 v;
            v.x = a0 * scale + b[f2 * 2];
            v.y = a1 * scale + b[f2 * 2 + 1];
            *(float2*)&out[(size_t)node * OUT_F + f2 * 2] = v;
        }
    }
}

extern "C" void kernel_launch(void* const* d_in, const int* in_sizes, int n_in,
                              void* d_out, int out_size, void* d_ws, size_t ws_size,
                              hipStream_t stream) {
    const float* x   = (const float*)d_in[0];
    const int*   src = (const int*)d_in[1];
    const int*   dst = (const int*)d_in[2];
    const float* W   = (const float*)d_in[3];
    const float* b   = (const float*)d_in[4];
    float* out = (float*)d_out;

    const int n  = in_sizes[0] / IN_F;   // 100000
    const int ne = in_sizes[1];          // 1000000

    const int nb = (n + BKT - 1) / BKT;  // 782 buckets (<= 1024)
    const int m  = 2 * nb * BLK1;        // cnt matrix size (800768)

    int* cnt        = (int*)d_ws;                  // m
    int* partials   = cnt + m;                     // 1024
    unsigned* tmp   = (unsigned*)(partials + 1024);// 2*ne
    int* deg_out    = (int*)(tmp + 2 * (size_t)ne);// n
    unsigned short* h = (unsigned short*)(deg_out + n);  // n*64 bf16

    const int nb_scan = (m + 1023) / 1024;         // 782 (<= 1024)

    k_coarse<<<BLK1, 256, 0, stream>>>(src, dst, cnt, nb, ne);
    k_scan1<<<nb_scan, 256, 0, stream>>>(cnt, cnt, partials, m);
    k_scan2<<<1, 1024, 0, stream>>>(partials, nb_scan);
    k_part<<<BLK1, 256, 0, stream>>>(src, dst, cnt, partials, tmp, nb, ne);
    k_fine_src<<<nb, 256, 0, stream>>>(cnt, partials, tmp, deg_out, n, nb, ne);
    k_gemm<<<(n + 127) / 128, 256, 0, stream>>>(x, W, deg_out, h, n);
    k_agg<<<nb, 512, 0, stream>>>(cnt, partials, tmp, (const unsigned*)h, b, out, n, nb, ne);
}